// Round 5
// baseline (153.654 us; speedup 1.0000x reference)
//
#include <hip/hip_runtime.h>
#include <stdint.h>

#define NB 1024
#define BB 256
#define KK 16
#define HH 64
#define WW 64
#define F_FULL 144
#define HDIM 128
#define CDIM 16
#define KPAD 160
#define APITCH 160   // A LDS pitch (bf16) == KPAD, packed. Banking fixed by XOR swizzle on the
                     // 16-B granule index (gran^(row&7)): gwrite stores AND GEMM1 b128 reads both
                     // land 8 uniform bank-starts (floor). Raw 160 without swizzle was R3's 2x
                     // conflict regression. 2 bufs = 40960 B -> 4 blocks/CU (full 160 KB pool).
#define HPITCH 136   // h LDS pitch (bf16)
#define ABYTES (64 * APITCH * 2)   // 20480
#define NCTR 128

typedef __bf16 bf16x8 __attribute__((ext_vector_type(8)));
typedef float f32x4 __attribute__((ext_vector_type(4)));

// ---------------- ws layout ----------------
// [0,512)      : int counters[128]
// [1024, ..)   : W1t bf16 [16][128][160]
// [.., ..)     : W2b bf16 [16][128]
// [.., ..)     : zt u8 (H,W,B,K)
#define W1T_OFF 1024
#define W1T_BYTES (16 * HDIM * KPAD * 2)
#define W2B_OFF (W1T_OFF + W1T_BYTES)
#define W2B_BYTES (CDIM * HDIM * 2)
#define ZT_OFF (W2B_OFF + W2B_BYTES)

__device__ __forceinline__ unsigned short bf16_bits(float v) {
    __bf16 b = (__bf16)v;
    return __builtin_bit_cast(unsigned short, b);
}

// A-tile LDS addressing: row-major pitch 160 shorts, 16-B granule index XOR-
// swizzled by (row&7). gran in [0,20): 0..17 = data k[0,144), 18..19 = pad.
// Reads and writes MUST both use this mapping (both-sides-or-neither).
__device__ __forceinline__ int a_off(int row, int gran) {
    return row * APITCH + (((gran & ~7) | ((gran & 7) ^ (row & 7))) << 3);
}

// Fused prep (R0 version — measured ~8-9 us): blocks [0,4096) transpose
// z -> zt ; [4096,5376) build W1t ; [5376,5384) build W2b + zero counters.
#define TP 144
__global__ __launch_bounds__(256) void prep_kernel(
    const int* __restrict__ z, const float* __restrict__ W1,
    const float* __restrict__ W2, uint8_t* __restrict__ zt,
    unsigned short* __restrict__ W1t, unsigned short* __restrict__ W2b,
    int* __restrict__ counters) {
    int bid = blockIdx.x;
    int t = threadIdx.x;
    if (bid < 4096) {
        __shared__ uint8_t tile[32 * TP];   // tile[c][r], pitch 144
        int bx = bid & 127;                 // c tile
        int by = bid >> 7;                  // r tile, 0..31
        int c0 = bx * 32, r0 = by * 128;
#pragma unroll
        for (int i = 0; i < 4; ++i) {
            int lin = i * 256 + t;
            int c = lin & 31;
            int rq = lin >> 5;
            uchar4 v;
            v.x = (uint8_t)z[(size_t)(r0 + rq * 4 + 0) * 4096 + c0 + c];
            v.y = (uint8_t)z[(size_t)(r0 + rq * 4 + 1) * 4096 + c0 + c];
            v.z = (uint8_t)z[(size_t)(r0 + rq * 4 + 2) * 4096 + c0 + c];
            v.w = (uint8_t)z[(size_t)(r0 + rq * 4 + 3) * 4096 + c0 + c];
            *(uchar4*)(tile + c * TP + rq * 4) = v;
        }
        __syncthreads();
        int cy = t >> 3, rx = t & 7;
        uint4 v = *(const uint4*)(tile + cy * TP + rx * 16);
        *(uint4*)(zt + (size_t)(c0 + cy) * 4096 + r0 + rx * 16) = v;
    } else if (bid < 5376) {
        int idx = (bid - 4096) * 256 + t;   // 16*128*160 = 327680
        int k = idx % KPAD;
        int h = (idx / KPAD) % HDIM;
        int s = idx / (KPAD * HDIM);
        int drop = 4 * KK + s;
        float val = 0.0f;
        if (k < F_FULL && k != drop) {
            int src = k - (k > drop ? 1 : 0);
            val = W1[src * HDIM + h];
        }
        W1t[idx] = bf16_bits(val);
    } else {
        int idx = (bid - 5376) * 256 + t;   // 2048 total
        if (idx < CDIM * HDIM) {
            int k = idx % HDIM;
            int c = idx / HDIM;
            W2b[idx] = bf16_bits(W2[k * CDIM + c]);
        }
        if (bid == 5376 && t < NCTR) counters[t] = 0;
    }
}

// Main fused MFMA kernel: one block per n; 4 b-tiles of 64, double-buffered
// A staging software-pipelined against compute (R0 schedule). Single change
// vs R4: packed+swizzled A pitch -> LDS 40960 B -> 4 blocks/CU so all 1024
// blocks (4 per CU) are co-resident: kernel time ~ 1 block latency, not 2.
// Pad granules 18,19 zeroed once for FINITENESS only (W1t k>=144 cols are
// zero, so pad*0=0 as long as pad bits aren't NaN; later sH-relu overwrites
// are finite and therefore safe — same invariant the R0/R4 kernels relied on).
__global__ __launch_bounds__(256, 4) void main_kernel(
    const uint8_t* __restrict__ zt, const unsigned short* __restrict__ W1t,
    const float* __restrict__ b1, const unsigned short* __restrict__ W2b,
    const float* __restrict__ b2, const int* __restrict__ bs,
    const int* __restrict__ ii, const int* __restrict__ jj,
    int* __restrict__ counters) {
    __shared__ __align__(16) unsigned char smem[2 * ABYTES];
    unsigned short* sA0 = (unsigned short*)smem;
    unsigned short* sA1 = (unsigned short*)(smem + ABYTES);

    int t = threadIdx.x;
    int n = blockIdx.x;
    int wave = t >> 6, lane = t & 63;
    int l15 = lane & 15, l4 = lane >> 4;

    int in_ = ii[n], jn = jj[n], sn = bs[n];

    // ---- B fragments: once per n (L2-hot) ----
    const unsigned short* w1s = W1t + (size_t)sn * (HDIM * KPAD);
    int n0 = wave * 32;
    bf16x8 Bf[2][5];
#pragma unroll
    for (int nt = 0; nt < 2; ++nt)
#pragma unroll
        for (int ks = 0; ks < 5; ++ks)
            Bf[nt][ks] = *(const bf16x8*)(w1s + (n0 + nt * 16 + l15) * KPAD + ks * 32 + l4 * 8);
    bf16x8 Bf2[4];
#pragma unroll
    for (int ks = 0; ks < 4; ++ks)
        Bf2[ks] = *(const bf16x8*)(W2b + l15 * HDIM + ks * 32 + l4 * 8);
    float b1v0 = b1[n0 + l15], b1v1 = b1[n0 + 16 + l15];
    float b2v = b2[l15];

    // ---- make A pad granules 18,19 finite in BOTH buffers (one write/thread)
    {
        int b = t & 63, gran = 18 + ((t >> 6) & 1);
        unsigned short* dstp = (t >= 128) ? sA1 : sA0;
        *(uint4*)(dstp + a_off(b, gran)) = make_uint4(0, 0, 0, 0);
    }

    // ---- gather: 576 items (9 pixels x 64 b) per tile; thread t: items t, t+256, (+512 if t<64)
    uint4 g0, g1, g2;
    auto gload = [&](int tile) {
        int b = (t & 63) + tile * 64;
        int p0 = t >> 6;                                  // 0..3
        int ni0 = (in_ + p0 / 3 - 1) & (HH - 1);
        int nj0 = (jn + p0 % 3 - 1) & (WW - 1);
        g0 = *(const uint4*)(zt + (((size_t)(ni0 * WW + nj0) * BB + b) << 4));
        int p1 = p0 + 4;                                  // 4..7
        int ni1 = (in_ + p1 / 3 - 1) & (HH - 1);
        int nj1 = (jn + p1 % 3 - 1) & (WW - 1);
        g1 = *(const uint4*)(zt + (((size_t)(ni1 * WW + nj1) * BB + b) << 4));
        if (t < 64) {                                     // p=8 -> di=+1, dj=+1
            int ni2 = (in_ + 1) & (HH - 1);
            int nj2 = (jn + 1) & (WW - 1);
            g2 = *(const uint4*)(zt + (((size_t)(ni2 * WW + nj2) * BB + b) << 4));
        }
    };
    auto gwrite = [&](unsigned short* dst) {
        int b = t & 63;
        int p0 = t >> 6;
        auto conv = [&](uint4 raw, int p) {
            const uint8_t* bytes = (const uint8_t*)&raw;
            union { __bf16 h[16]; uint4 q[2]; } u;
#pragma unroll
            for (int k = 0; k < 16; ++k)
                u.h[k] = (__bf16)((float)bytes[k] * (1.0f / 15.0f));
            *(uint4*)(dst + a_off(b, 2 * p)) = u.q[0];
            *(uint4*)(dst + a_off(b, 2 * p + 1)) = u.q[1];
        };
        conv(g0, p0);
        conv(g1, p0 + 4);
        if (t < 64) conv(g2, 8);
    };

    gload(0);
    gwrite(sA0);
    int err = 0;
    size_t tbase = ((size_t)(in_ * WW + jn) * BB) << 4;

    for (int tile = 0; tile < 4; ++tile) {
        unsigned short* sA = (tile & 1) ? sA1 : sA0;
        unsigned short* sH = sA;                    // overlay after GEMM1 reads done
        unsigned short* sAnext = (tile & 1) ? sA0 : sA1;

        if (tile < 3) gload(tile + 1);              // loads in flight across compute
        __syncthreads();                            // sA staging complete

        // ---- GEMM1: M=64 x N=128 x K=160, wave owns 32 N-cols, 4 M-tiles ----
        f32x4 acc[4][2] = {};
#pragma unroll
        for (int mt = 0; mt < 4; ++mt) {
            bf16x8 Af[5];
#pragma unroll
            for (int ks = 0; ks < 5; ++ks)
                Af[ks] = *(const bf16x8*)(sA + a_off(mt * 16 + l15, 4 * ks + l4 * 0 + l4));
#pragma unroll
            for (int ks = 0; ks < 5; ++ks) {
                acc[mt][0] = __builtin_amdgcn_mfma_f32_16x16x32_bf16(Af[ks], Bf[0][ks], acc[mt][0], 0, 0, 0);
                acc[mt][1] = __builtin_amdgcn_mfma_f32_16x16x32_bf16(Af[ks], Bf[1][ks], acc[mt][1], 0, 0, 0);
            }
        }
        __syncthreads();   // all sA reads done before sH overlay writes

        // ---- bias + relu -> sH bf16 [b][h] ----
#pragma unroll
        for (int mt = 0; mt < 4; ++mt)
#pragma unroll
            for (int nt = 0; nt < 2; ++nt) {
                float bv = nt ? b1v1 : b1v0;
                int hcol = n0 + nt * 16 + l15;
#pragma unroll
                for (int r = 0; r < 4; ++r) {
                    int b = mt * 16 + l4 * 4 + r;
                    float v = fmaxf(acc[mt][nt][r] + bv, 0.0f);
                    sH[b * HPITCH + hcol] = bf16_bits(v);
                }
            }
        __syncthreads();

        // ---- GEMM2: M=64 x N=16 x K=128; wave owns M-tile `wave` ----
        f32x4 acc2 = {};
#pragma unroll
        for (int ks = 0; ks < 4; ++ks) {
            bf16x8 Af = *(const bf16x8*)(sH + (wave * 16 + l15) * HPITCH + ks * 32 + l4 * 8);
            acc2 = __builtin_amdgcn_mfma_f32_16x16x32_bf16(Af, Bf2[ks], acc2, 0, 0, 0);
        }

        // ---- in-register argmax over c=l15 within each 16-lane group ----
#pragma unroll
        for (int r = 0; r < 4; ++r) {
            float v = acc2[r] + b2v;
            int idx = l15;
#pragma unroll
            for (int m = 1; m < 16; m <<= 1) {
                float ov = __shfl_xor(v, m);
                int oi = __shfl_xor(idx, m);
                // first-max semantics (jnp.argmax): on tie keep lower index
                if (ov > v || (ov == v && oi < idx)) { v = ov; idx = oi; }
            }
            int bg = tile * 64 + wave * 16 + l4 * 4 + r;
            int tgt = zt[tbase + ((size_t)bg << 4) + sn];
            unsigned long long mm = __ballot(l15 == 0 && idx != tgt);
            err += (int)__popcll(mm);
        }

        // ---- stage next tile (vmcnt waits only drain the needed loads) ----
        if (tile < 3) gwrite(sAnext);
    }

    if (lane == 0) atomicAdd(&counters[n & (NCTR - 1)], err);
}

__global__ void finalize_kernel(const int* __restrict__ counters, float* __restrict__ out) {
    int t = threadIdx.x;   // 64 threads
    int s = counters[t] + counters[t + 64];
#pragma unroll
    for (int m = 32; m; m >>= 1) s += __shfl_down(s, m);
    if (t == 0) out[0] = (float)s / (float)(NB * BB);
}

extern "C" void kernel_launch(void* const* d_in, const int* in_sizes, int n_in,
                              void* d_out, int out_size, void* d_ws, size_t ws_size,
                              hipStream_t stream) {
    const int* z = (const int*)d_in[0];
    const int* bs = (const int*)d_in[1];
    const int* ii = (const int*)d_in[2];
    const int* jj = (const int*)d_in[3];
    const float* W1 = (const float*)d_in[4];
    const float* b1 = (const float*)d_in[5];
    const float* W2 = (const float*)d_in[6];
    const float* b2 = (const float*)d_in[7];
    float* out = (float*)d_out;

    uint8_t* ws = (uint8_t*)d_ws;
    int* counters = (int*)ws;
    unsigned short* W1t = (unsigned short*)(ws + W1T_OFF);
    unsigned short* W2b = (unsigned short*)(ws + W2B_OFF);
    uint8_t* zt = ws + ZT_OFF;

    prep_kernel<<<5384, 256, 0, stream>>>(z, W1, W2, zt, W1t, W2b, counters);
    main_kernel<<<NB, 256, 0, stream>>>(zt, W1t, b1, W2b, b2, bs, ii, jj, counters);
    finalize_kernel<<<1, 64, 0, stream>>>(counters, out);
}

// Round 6
// 144.602 us; speedup vs baseline: 1.0626x; 1.0626x over previous
//
#include <hip/hip_runtime.h>
#include <stdint.h>

#define NB 1024
#define BB 256
#define KK 16
#define HH 64
#define WW 64
#define F_FULL 144
#define HDIM 128
#define CDIM 16
#define KPAD 160
#define HPITCH 136               // h LDS pitch (bf16)
#define PBYTES 2048              // per-pixel LDS bytes: 64 b x 16 k x 2 B
#define ABYTES (10 * PBYTES)     // 20480 per buffer; pixel 9 = zero pad (K 144->160)
#define NCTR 128

typedef __bf16 bf16x8 __attribute__((ext_vector_type(8)));
typedef float f32x4 __attribute__((ext_vector_type(4)));

// ---------------- ws layout ----------------
// [0,512)      : int counters[128]
// [1024, ..)   : W1t bf16 [16][128][160]
// [.., ..)     : W2b bf16 [16][128]
// [.., ..)     : ztb bf16 (H,W,B,K), pre-scaled by 1/15
#define W1T_OFF 1024
#define W1T_BYTES (16 * HDIM * KPAD * 2)
#define W2B_OFF (W1T_OFF + W1T_BYTES)
#define W2B_BYTES (CDIM * HDIM * 2)
#define ZTB_OFF (W2B_OFF + W2B_BYTES)   // 660480, 16-B aligned

__device__ __forceinline__ unsigned short bf16_bits(float v) {
    __bf16 b = (__bf16)v;
    return __builtin_bit_cast(unsigned short, b);
}

// Fused prep: blocks [0,4096) transpose z -> ztb (bf16, /15) ; [4096,5376)
// build W1t ; [5376,5384) build W2b ; block 5376 zeroes the 128 counters.
#define TP 144
__global__ __launch_bounds__(256) void prep_kernel(
    const int* __restrict__ z, const float* __restrict__ W1,
    const float* __restrict__ W2, uint8_t* __restrict__ ztb,
    unsigned short* __restrict__ W1t, unsigned short* __restrict__ W2b,
    int* __restrict__ counters) {
    int bid = blockIdx.x;
    int t = threadIdx.x;
    if (bid < 4096) {
        __shared__ uint8_t tile[32 * TP];   // tile[c][r], pitch 144
        int bx = bid & 127;                 // c tile (spatial h*64+w)
        int by = bid >> 7;                  // r tile (b*16+k), 0..31
        int c0 = bx * 32, r0 = by * 128;
#pragma unroll
        for (int i = 0; i < 4; ++i) {
            int lin = i * 256 + t;
            int c = lin & 31;
            int rq = lin >> 5;
            uchar4 v;
            v.x = (uint8_t)z[(size_t)(r0 + rq * 4 + 0) * 4096 + c0 + c];
            v.y = (uint8_t)z[(size_t)(r0 + rq * 4 + 1) * 4096 + c0 + c];
            v.z = (uint8_t)z[(size_t)(r0 + rq * 4 + 2) * 4096 + c0 + c];
            v.w = (uint8_t)z[(size_t)(r0 + rq * 4 + 3) * 4096 + c0 + c];
            *(uchar4*)(tile + c * TP + rq * 4) = v;
        }
        __syncthreads();
        int cy = t >> 3, rx = t & 7;
        uint4 v = *(const uint4*)(tile + cy * TP + rx * 16);
        const uint8_t* bytes = (const uint8_t*)&v;
        union { __bf16 h[16]; uint4 q[2]; } u;
#pragma unroll
        for (int k = 0; k < 16; ++k)
            u.h[k] = (__bf16)((float)bytes[k] * (1.0f / 15.0f));
        uint4* dst = (uint4*)(ztb + (((size_t)(c0 + cy) * 4096 + r0 + rx * 16) << 1));
        dst[0] = u.q[0];
        dst[1] = u.q[1];
    } else if (bid < 5376) {
        int idx = (bid - 4096) * 256 + t;   // 16*128*160 = 327680
        int k = idx % KPAD;
        int h = (idx / KPAD) % HDIM;
        int s = idx / (KPAD * HDIM);
        int drop = 4 * KK + s;
        float val = 0.0f;
        if (k < F_FULL && k != drop) {
            int src = k - (k > drop ? 1 : 0);
            val = W1[src * HDIM + h];
        }
        W1t[idx] = bf16_bits(val);
    } else {
        int idx = (bid - 5376) * 256 + t;   // 2048 total
        if (idx < CDIM * HDIM) {
            int k = idx % HDIM;
            int c = idx / HDIM;
            W2b[idx] = bf16_bits(W2[k * CDIM + c]);
        }
        if (bid == 5376 && t < NCTR) counters[t] = 0;
    }
}

// Main fused MFMA kernel: one block per n; 4 b-tiles of 64, double-buffered.
// A staging is now pure async DMA: 18 global_load_lds(16B) per tile from the
// pre-converted bf16 ztb into pixel-major LDS [10][64][16] (pixel 9 = pad).
// No gather VGPRs, no u8->bf16 conversion VALU, no gwrite tail. Live set
// ~110 regs -> fits the (256,4) budget (R3/R5 spilled at ~146). LDS
// 2x20480=40960 -> 4 blocks/CU, all 1024 blocks co-resident (proven R5).
__global__ __launch_bounds__(256, 4) void main_kernel(
    const uint8_t* __restrict__ ztb, const unsigned short* __restrict__ W1t,
    const float* __restrict__ b1, const unsigned short* __restrict__ W2b,
    const float* __restrict__ b2, const int* __restrict__ bs,
    const int* __restrict__ ii, const int* __restrict__ jj,
    int* __restrict__ counters) {
    __shared__ __align__(16) unsigned char smem[2 * ABYTES];

    int t = threadIdx.x;
    int n = blockIdx.x;
    int wave = t >> 6, lane = t & 63;
    int l15 = lane & 15, l4 = lane >> 4;

    int in_ = ii[n], jn = jj[n], sn = bs[n];

    // ---- async A-tile staging: 18 wave-items (9 pixels x 2 halves), waves
    // round-robin. LDS dest wave-uniform (p,half); global src per-lane.
    auto stage = [&](int buf, int tile) {
#pragma unroll
        for (int j = 0; j < 5; ++j) {
            int it = wave + j * 4;
            if (it < 18) {                      // wave-uniform branch
                int p = it >> 1, half = it & 1;
                int di = (p * 11) >> 5;         // p/3 for p in [0,9)
                int dj = p - di * 3;
                int ni = (in_ + di - 1) & (HH - 1);
                int nj = (jn + dj - 1) & (WW - 1);
                const uint8_t* src = ztb + ((size_t)(ni * WW + nj) << 13)
                                   + ((tile * 64 + half * 32) << 5) + lane * 16;
                __builtin_amdgcn_global_load_lds(
                    (const __attribute__((address_space(1))) void*)src,
                    (__attribute__((address_space(3))) void*)(smem + buf * ABYTES + p * PBYTES + half * 1024),
                    16, 0, 0);
            }
        }
    };

    stage(0, 0);   // in flight during prologue

    // ---- B fragments: once per n (L2-hot W1t slice) ----
    const unsigned short* w1s = W1t + (size_t)sn * (HDIM * KPAD);
    int n0 = wave * 32;
    bf16x8 Bf[2][5];
#pragma unroll
    for (int nt = 0; nt < 2; ++nt)
#pragma unroll
        for (int ks = 0; ks < 5; ++ks)
            Bf[nt][ks] = *(const bf16x8*)(w1s + (n0 + nt * 16 + l15) * KPAD + ks * 32 + l4 * 8);
    float b1v0 = b1[n0 + l15], b1v1 = b1[n0 + 16 + l15];
    float b2v = b2[l15];

    // ---- zero pad pixel 9 in BOTH buffers (disjoint from staging writes;
    // sH overlay spans only shorts [0,8704) < pixel-9 base 9216 -> stays 0)
    {
        int buf = t >> 7;
        *(uint4*)(smem + buf * ABYTES + 9 * PBYTES + (t & 127) * 16) = make_uint4(0, 0, 0, 0);
    }

    int err = 0, cur = 0;
    size_t tb8 = ((size_t)(in_ * WW + jn) << 13);   // target pixel base in ztb

    for (int tile = 0; tile < 4; ++tile) {
        __syncthreads();                            // drains vmcnt -> buf[cur] staged
        if (tile < 3) stage(cur ^ 1, tile + 1);     // async during GEMM1

        // preload this tile's 4 targets (used after GEMM2)
        int bg0 = tile * 64 + wave * 16 + l4 * 4;
        unsigned short tv[4];
#pragma unroll
        for (int r = 0; r < 4; ++r)
            tv[r] = *(const unsigned short*)(ztb + tb8 + ((size_t)(bg0 + r) << 5) + (sn << 1));

        const unsigned short* sAs = (const unsigned short*)(smem + cur * ABYTES);

        // ---- GEMM1: M=64 x N=128 x K=160 (10 pixels x 16), wave owns 32 N-cols
        f32x4 acc[4][2] = {};
#pragma unroll
        for (int mt = 0; mt < 4; ++mt) {
            bf16x8 Af[5];
#pragma unroll
            for (int ks = 0; ks < 5; ++ks)
                Af[ks] = *(const bf16x8*)(sAs + (2 * ks + (l4 >> 1)) * 1024 + (mt * 16 + l15) * 16 + (l4 & 1) * 8);
#pragma unroll
            for (int ks = 0; ks < 5; ++ks) {
                acc[mt][0] = __builtin_amdgcn_mfma_f32_16x16x32_bf16(Af[ks], Bf[0][ks], acc[mt][0], 0, 0, 0);
                acc[mt][1] = __builtin_amdgcn_mfma_f32_16x16x32_bf16(Af[ks], Bf[1][ks], acc[mt][1], 0, 0, 0);
            }
        }
        __syncthreads();   // all sA reads done before sH overlay writes

        // ---- bias + relu -> sH bf16 [b][h] (overlays buf[cur]) ----
        unsigned short* sH = (unsigned short*)(smem + cur * ABYTES);
#pragma unroll
        for (int mt = 0; mt < 4; ++mt)
#pragma unroll
            for (int nt = 0; nt < 2; ++nt) {
                float bv = nt ? b1v1 : b1v0;
                int hcol = n0 + nt * 16 + l15;
#pragma unroll
                for (int r = 0; r < 4; ++r) {
                    int b = mt * 16 + l4 * 4 + r;
                    float v = fmaxf(acc[mt][nt][r] + bv, 0.0f);
                    sH[b * HPITCH + hcol] = bf16_bits(v);
                }
            }
        __syncthreads();

        // ---- GEMM2: M=64 x N=16 x K=128; Bf2 per-tile (L1-hot, acc is dead)
        f32x4 acc2 = {};
#pragma unroll
        for (int ks = 0; ks < 4; ++ks) {
            bf16x8 Bf2 = *(const bf16x8*)(W2b + l15 * HDIM + ks * 32 + l4 * 8);
            bf16x8 Af = *(const bf16x8*)(sH + (wave * 16 + l15) * HPITCH + ks * 32 + l4 * 8);
            acc2 = __builtin_amdgcn_mfma_f32_16x16x32_bf16(Af, Bf2, acc2, 0, 0, 0);
        }

        // ---- in-register argmax over c=l15 within each 16-lane group ----
#pragma unroll
        for (int r = 0; r < 4; ++r) {
            float v = acc2[r] + b2v;
            int idx = l15;
#pragma unroll
            for (int m = 1; m < 16; m <<= 1) {
                float ov = __shfl_xor(v, m);
                int oi = __shfl_xor(idx, m);
                // first-max semantics (jnp.argmax): on tie keep lower index
                if (ov > v || (ov == v && oi < idx)) { v = ov; idx = oi; }
            }
            // recover integer target from bf16(val/15): exact (rel err 2^-9)
            float tf = __builtin_bit_cast(float, (uint32_t)tv[r] << 16);
            int tgt = (int)(tf * 15.0f + 0.5f);
            unsigned long long mm = __ballot(l15 == 0 && idx != tgt);
            err += (int)__popcll(mm);
        }

        cur ^= 1;
    }

    if (lane == 0) atomicAdd(&counters[n & (NCTR - 1)], err);
}

__global__ void finalize_kernel(const int* __restrict__ counters, float* __restrict__ out) {
    int t = threadIdx.x;   // 64 threads
    int s = counters[t] + counters[t + 64];
#pragma unroll
    for (int m = 32; m; m >>= 1) s += __shfl_down(s, m);
    if (t == 0) out[0] = (float)s / (float)(NB * BB);
}

extern "C" void kernel_launch(void* const* d_in, const int* in_sizes, int n_in,
                              void* d_out, int out_size, void* d_ws, size_t ws_size,
                              hipStream_t stream) {
    const int* z = (const int*)d_in[0];
    const int* bs = (const int*)d_in[1];
    const int* ii = (const int*)d_in[2];
    const int* jj = (const int*)d_in[3];
    const float* W1 = (const float*)d_in[4];
    const float* b1 = (const float*)d_in[5];
    const float* W2 = (const float*)d_in[6];
    const float* b2 = (const float*)d_in[7];
    float* out = (float*)d_out;

    uint8_t* ws = (uint8_t*)d_ws;
    int* counters = (int*)ws;
    unsigned short* W1t = (unsigned short*)(ws + W1T_OFF);
    unsigned short* W2b = (unsigned short*)(ws + W2B_OFF);
    uint8_t* ztb = ws + ZTB_OFF;

    prep_kernel<<<5384, 256, 0, stream>>>(z, W1, W2, ztb, W1t, W2b, counters);
    main_kernel<<<NB, 256, 0, stream>>>(ztb, W1t, b1, W2b, b2, bs, ii, jj, counters);
    finalize_kernel<<<1, 64, 0, stream>>>(counters, out);
}

// Round 7
// 144.572 us; speedup vs baseline: 1.0628x; 1.0002x over previous
//
#include <hip/hip_runtime.h>
#include <stdint.h>

#define NB 1024
#define BB 256
#define KK 16
#define HH 64
#define WW 64
#define F_FULL 144
#define HDIM 128
#define CDIM 16
#define KPAD 160
#define APITCH 168   // A LDS pitch (bf16): 336 B rows; both GEMM1 b128 reads AND gwrite b128
                     // stores hit the 8-starts bank floor ((84*lane) mod 32 covers 8 values).
#define HPITCH 136   // h LDS pitch (bf16)
#define ABYTES (64 * APITCH * 2)   // 21504
#define HBYTES (64 * HPITCH * 2)   // 17408  (separate sH: deletes the overlay barrier)
#define NCTR 128

typedef __bf16 bf16x8 __attribute__((ext_vector_type(8)));
typedef float f32x4 __attribute__((ext_vector_type(4)));

// ---------------- ws layout ----------------
// [0,512)      : int counters[128]
// [1024, ..)   : W1t bf16 [16][128][160]
// [.., ..)     : W2b bf16 [16][128]
// [.., ..)     : zt u8 (H,W,B,K)
#define W1T_OFF 1024
#define W1T_BYTES (16 * HDIM * KPAD * 2)
#define W2B_OFF (W1T_OFF + W1T_BYTES)
#define W2B_BYTES (CDIM * HDIM * 2)
#define ZT_OFF (W2B_OFF + W2B_BYTES)

__device__ __forceinline__ unsigned short bf16_bits(float v) {
    __bf16 b = (__bf16)v;
    return __builtin_bit_cast(unsigned short, b);
}

// Fused prep (R0 version — measured ~8-9 us): blocks [0,4096) transpose
// z -> zt ; [4096,5376) build W1t ; [5376,5384) build W2b + zero counters.
#define TP 144
__global__ __launch_bounds__(256) void prep_kernel(
    const int* __restrict__ z, const float* __restrict__ W1,
    const float* __restrict__ W2, uint8_t* __restrict__ zt,
    unsigned short* __restrict__ W1t, unsigned short* __restrict__ W2b,
    int* __restrict__ counters) {
    int bid = blockIdx.x;
    int t = threadIdx.x;
    if (bid < 4096) {
        __shared__ uint8_t tile[32 * TP];   // tile[c][r], pitch 144
        int bx = bid & 127;                 // c tile
        int by = bid >> 7;                  // r tile, 0..31
        int c0 = bx * 32, r0 = by * 128;
#pragma unroll
        for (int i = 0; i < 4; ++i) {
            int lin = i * 256 + t;
            int c = lin & 31;
            int rq = lin >> 5;
            uchar4 v;
            v.x = (uint8_t)z[(size_t)(r0 + rq * 4 + 0) * 4096 + c0 + c];
            v.y = (uint8_t)z[(size_t)(r0 + rq * 4 + 1) * 4096 + c0 + c];
            v.z = (uint8_t)z[(size_t)(r0 + rq * 4 + 2) * 4096 + c0 + c];
            v.w = (uint8_t)z[(size_t)(r0 + rq * 4 + 3) * 4096 + c0 + c];
            *(uchar4*)(tile + c * TP + rq * 4) = v;
        }
        __syncthreads();
        int cy = t >> 3, rx = t & 7;
        uint4 v = *(const uint4*)(tile + cy * TP + rx * 16);
        *(uint4*)(zt + (size_t)(c0 + cy) * 4096 + r0 + rx * 16) = v;
    } else if (bid < 5376) {
        int idx = (bid - 4096) * 256 + t;   // 16*128*160 = 327680
        int k = idx % KPAD;
        int h = (idx / KPAD) % HDIM;
        int s = idx / (KPAD * HDIM);
        int drop = 4 * KK + s;
        float val = 0.0f;
        if (k < F_FULL && k != drop) {
            int src = k - (k > drop ? 1 : 0);
            val = W1[src * HDIM + h];
        }
        W1t[idx] = bf16_bits(val);
    } else {
        int idx = (bid - 5376) * 256 + t;   // 2048 total
        if (idx < CDIM * HDIM) {
            int k = idx % HDIM;
            int c = idx / HDIM;
            W2b[idx] = bf16_bits(W2[k * CDIM + c]);
        }
        if (bid == 5376 && t < NCTR) counters[t] = 0;
    }
}

// Main fused MFMA kernel: one block per n; 4 b-tiles of 64, double-buffered
// A staging software-pipelined against compute (R0 schedule, reg-staged).
// R7 changes vs the proven R4 kernel — chain-length cuts, not occupancy:
//  (1) sH gets its OWN buffer (no sA overlay) -> the mid-tile barrier between
//      GEMM1 and the relu-store is DELETED: 3 -> 2 barriers per tile, and
//      relu VALU can overlap GEMM1's MFMA tail. LDS 60416 -> 2 blocks/CU,
//      which R0..R6 showed is free (duration anti-correlates with occupancy).
//  (2) per-tile target bytes loaded at TILE START (latency hidden under
//      GEMM1) instead of between GEMM2 and the ballot.
//  (3) __launch_bounds__(256,2): 256-VGPR budget, zero spill risk (R3/R5
//      proved (256,4) spills at this live set).
__global__ __launch_bounds__(256, 2) void main_kernel(
    const uint8_t* __restrict__ zt, const unsigned short* __restrict__ W1t,
    const float* __restrict__ b1, const unsigned short* __restrict__ W2b,
    const float* __restrict__ b2, const int* __restrict__ bs,
    const int* __restrict__ ii, const int* __restrict__ jj,
    int* __restrict__ counters) {
    __shared__ __align__(16) unsigned char smem[2 * ABYTES + HBYTES];
    unsigned short* sA0 = (unsigned short*)smem;
    unsigned short* sA1 = (unsigned short*)(smem + ABYTES);
    unsigned short* sH = (unsigned short*)(smem + 2 * ABYTES);

    int t = threadIdx.x;
    int n = blockIdx.x;
    int wave = t >> 6, lane = t & 63;
    int l15 = lane & 15, l4 = lane >> 4;

    int in_ = ii[n], jn = jj[n], sn = bs[n];

    // ---- B fragments: once per n (L2-hot) ----
    const unsigned short* w1s = W1t + (size_t)sn * (HDIM * KPAD);
    int n0 = wave * 32;
    bf16x8 Bf[2][5];
#pragma unroll
    for (int nt = 0; nt < 2; ++nt)
#pragma unroll
        for (int ks = 0; ks < 5; ++ks)
            Bf[nt][ks] = *(const bf16x8*)(w1s + (n0 + nt * 16 + l15) * KPAD + ks * 32 + l4 * 8);
    bf16x8 Bf2[4];
#pragma unroll
    for (int ks = 0; ks < 4; ++ks)
        Bf2[ks] = *(const bf16x8*)(W2b + l15 * HDIM + ks * 32 + l4 * 8);
    float b1v0 = b1[n0 + l15], b1v1 = b1[n0 + 16 + l15];
    float b2v = b2[l15];

    // ---- zero A pad k in [144,168) for BOTH buffers ----
    if (t < 192) {
        int b = t / 3, part = t % 3;
        *(uint4*)(sA0 + b * APITCH + F_FULL + part * 8) = make_uint4(0, 0, 0, 0);
        *(uint4*)(sA1 + b * APITCH + F_FULL + part * 8) = make_uint4(0, 0, 0, 0);
    }

    // ---- gather: 576 items (9 pixels x 64 b) per tile; thread t: items t, t+256, (+512 if t<64)
    uint4 g0, g1, g2;
    auto gload = [&](int tile) {
        int b = (t & 63) + tile * 64;
        int p0 = t >> 6;                                  // 0..3
        int ni0 = (in_ + p0 / 3 - 1) & (HH - 1);
        int nj0 = (jn + p0 % 3 - 1) & (WW - 1);
        g0 = *(const uint4*)(zt + (((size_t)(ni0 * WW + nj0) * BB + b) << 4));
        int p1 = p0 + 4;                                  // 4..7
        int ni1 = (in_ + p1 / 3 - 1) & (HH - 1);
        int nj1 = (jn + p1 % 3 - 1) & (WW - 1);
        g1 = *(const uint4*)(zt + (((size_t)(ni1 * WW + nj1) * BB + b) << 4));
        if (t < 64) {                                     // p=8 -> di=+1, dj=+1
            int ni2 = (in_ + 1) & (HH - 1);
            int nj2 = (jn + 1) & (WW - 1);
            g2 = *(const uint4*)(zt + (((size_t)(ni2 * WW + nj2) * BB + b) << 4));
        }
    };
    auto gwrite = [&](unsigned short* dst) {
        int b = t & 63;
        int p0 = t >> 6;
        auto conv = [&](uint4 raw, int p) {
            const uint8_t* bytes = (const uint8_t*)&raw;
            union { __bf16 h[16]; uint4 q[2]; } u;
#pragma unroll
            for (int k = 0; k < 16; ++k)
                u.h[k] = (__bf16)((float)bytes[k] * (1.0f / 15.0f));
            uint4* d = (uint4*)(dst + b * APITCH + p * 16);
            d[0] = u.q[0];
            d[1] = u.q[1];
        };
        conv(g0, p0);
        conv(g1, p0 + 4);
        if (t < 64) conv(g2, 8);
    };

    gload(0);
    gwrite(sA0);
    int err = 0;
    size_t tbase = ((size_t)(in_ * WW + jn) * BB) << 4;

    for (int tile = 0; tile < 4; ++tile) {
        unsigned short* sA = (tile & 1) ? sA1 : sA0;
        unsigned short* sAnext = (tile & 1) ? sA0 : sA1;

        if (tile < 3) gload(tile + 1);              // loads in flight across compute
        __syncthreads();                            // sA staging complete (barrier 1)

        // early target loads: latency hides under GEMM1
        int bg0 = tile * 64 + wave * 16 + l4 * 4;
        int tv4[4];
#pragma unroll
        for (int r = 0; r < 4; ++r)
            tv4[r] = zt[tbase + ((size_t)(bg0 + r) << 4) + sn];

        // ---- GEMM1: M=64 x N=128 x K=160, wave owns 32 N-cols, 4 M-tiles ----
        f32x4 acc[4][2] = {};
#pragma unroll
        for (int mt = 0; mt < 4; ++mt) {
            bf16x8 Af[5];
#pragma unroll
            for (int ks = 0; ks < 5; ++ks)
                Af[ks] = *(const bf16x8*)(sA + (mt * 16 + l15) * APITCH + ks * 32 + l4 * 8);
#pragma unroll
            for (int ks = 0; ks < 5; ++ks) {
                acc[mt][0] = __builtin_amdgcn_mfma_f32_16x16x32_bf16(Af[ks], Bf[0][ks], acc[mt][0], 0, 0, 0);
                acc[mt][1] = __builtin_amdgcn_mfma_f32_16x16x32_bf16(Af[ks], Bf[1][ks], acc[mt][1], 0, 0, 0);
            }
        }

        // ---- bias + relu -> sH bf16 [b][h] (separate buffer: NO barrier here;
        // wave w writes h-cols n0..n0+32 only, read cross-wave after barrier 2)
#pragma unroll
        for (int mt = 0; mt < 4; ++mt)
#pragma unroll
            for (int nt = 0; nt < 2; ++nt) {
                float bv = nt ? b1v1 : b1v0;
                int hcol = n0 + nt * 16 + l15;
#pragma unroll
                for (int r = 0; r < 4; ++r) {
                    int b = mt * 16 + l4 * 4 + r;
                    float v = fmaxf(acc[mt][nt][r] + bv, 0.0f);
                    sH[b * HPITCH + hcol] = bf16_bits(v);
                }
            }
        __syncthreads();                            // sH complete (barrier 2)

        // ---- GEMM2: M=64 x N=16 x K=128; wave owns M-tile `wave` ----
        f32x4 acc2 = {};
#pragma unroll
        for (int ks = 0; ks < 4; ++ks) {
            bf16x8 Af = *(const bf16x8*)(sH + (wave * 16 + l15) * HPITCH + ks * 32 + l4 * 8);
            acc2 = __builtin_amdgcn_mfma_f32_16x16x32_bf16(Af, Bf2[ks], acc2, 0, 0, 0);
        }

        // ---- in-register argmax over c=l15 within each 16-lane group ----
#pragma unroll
        for (int r = 0; r < 4; ++r) {
            float v = acc2[r] + b2v;
            int idx = l15;
#pragma unroll
            for (int m = 1; m < 16; m <<= 1) {
                float ov = __shfl_xor(v, m);
                int oi = __shfl_xor(idx, m);
                // first-max semantics (jnp.argmax): on tie keep lower index
                if (ov > v || (ov == v && oi < idx)) { v = ov; idx = oi; }
            }
            unsigned long long mm = __ballot(l15 == 0 && idx != tv4[r]);
            err += (int)__popcll(mm);
        }

        // ---- stage next tile (vmcnt waits only drain the needed loads) ----
        if (tile < 3) gwrite(sAnext);
    }

    if (lane == 0) atomicAdd(&counters[n & (NCTR - 1)], err);
}

__global__ void finalize_kernel(const int* __restrict__ counters, float* __restrict__ out) {
    int t = threadIdx.x;   // 64 threads
    int s = counters[t] + counters[t + 64];
#pragma unroll
    for (int m = 32; m; m >>= 1) s += __shfl_down(s, m);
    if (t == 0) out[0] = (float)s / (float)(NB * BB);
}

extern "C" void kernel_launch(void* const* d_in, const int* in_sizes, int n_in,
                              void* d_out, int out_size, void* d_ws, size_t ws_size,
                              hipStream_t stream) {
    const int* z = (const int*)d_in[0];
    const int* bs = (const int*)d_in[1];
    const int* ii = (const int*)d_in[2];
    const int* jj = (const int*)d_in[3];
    const float* W1 = (const float*)d_in[4];
    const float* b1 = (const float*)d_in[5];
    const float* W2 = (const float*)d_in[6];
    const float* b2 = (const float*)d_in[7];
    float* out = (float*)d_out;

    uint8_t* ws = (uint8_t*)d_ws;
    int* counters = (int*)ws;
    unsigned short* W1t = (unsigned short*)(ws + W1T_OFF);
    unsigned short* W2b = (unsigned short*)(ws + W2B_OFF);
    uint8_t* zt = ws + ZT_OFF;

    prep_kernel<<<5384, 256, 0, stream>>>(z, W1, W2, zt, W1t, W2b, counters);
    main_kernel<<<NB, 256, 0, stream>>>(zt, W1t, b1, W2b, b2, bs, ii, jj, counters);
    finalize_kernel<<<1, 64, 0, stream>>>(counters, out);
}